// Round 5
// baseline (333.007 us; speedup 1.0000x reference)
//
#include <hip/hip_runtime.h>
#include <hip/hip_bf16.h>

#define IN_DIM 1024
#define OUT_DIM 1024
#define NE 8
#define NT 8192
#define KE (NE*IN_DIM)      // 8192
#define KPAD 64
#define KTOT (KE+KPAD)      // 8256 (WeT width, incl bias cols)
#define XBW (IN_DIM+64)     // 1088 (xb width: 1024 x + 64 gate-pad)
#define BM 256
#define BN 128
#define BK 64
#define NKT 129             // 128 expert tiles + 1 bias tile

typedef unsigned short u16;
typedef __attribute__((ext_vector_type(4))) float f32x4;
typedef __attribute__((ext_vector_type(8))) short short8;

__device__ inline u16 f2bf(float f){
  unsigned u = __float_as_uint(f);
  return (u16)((u + 0x7fffu + ((u>>16)&1u)) >> 16);   // RNE
}

__device__ inline void gload16(const void* g, void* l){
  __builtin_amdgcn_global_load_lds(
    (const __attribute__((address_space(1))) void*)g,
    (__attribute__((address_space(3))) void*)l, 16, 0, 0);
}

// ---- fused: gates = softmax(x@Wg+bg) (f32); xb[n][k]=bf16(x[n,k]);
//      xb[n][1024+c] = bf16(gate_c) (c<8) else 0.  One wave per token. ----
__global__ void k_gx(const float* __restrict__ x, const float* __restrict__ Wg,
                     const float* __restrict__ bg, float* __restrict__ gates,
                     u16* __restrict__ xb){
  int lane = threadIdx.x & 63;
  int n = blockIdx.x*4 + (threadIdx.x>>6);
  const float* xr = x + (size_t)n*IN_DIM;
  float4 xl0 = *(const float4*)(xr + lane*8);
  float4 xl1 = *(const float4*)(xr + lane*8 + 4);
  float4 xh0 = *(const float4*)(xr + 512 + lane*8);
  float4 xh1 = *(const float4*)(xr + 512 + lane*8 + 4);
  float p[NE];
  #pragma unroll
  for(int e=0;e<NE;e++) p[e]=0.f;
  const float* wl = Wg + (size_t)(lane*8)*NE;
  const float* wh = Wg + (size_t)(512 + lane*8)*NE;
  #pragma unroll
  for(int j=0;j<4;j++){
    #pragma unroll
    for(int e=0;e<NE;e++){
      p[e] = fmaf((&xl0.x)[j], wl[(size_t)j*NE+e], p[e]);
      p[e] = fmaf((&xh0.x)[j], wh[(size_t)j*NE+e], p[e]);
      p[e] = fmaf((&xl1.x)[j], wl[(size_t)(j+4)*NE+e], p[e]);
      p[e] = fmaf((&xh1.x)[j], wh[(size_t)(j+4)*NE+e], p[e]);
    }
  }
  #pragma unroll
  for(int e=0;e<NE;e++){
    float v = p[e];
    #pragma unroll
    for(int off=32;off;off>>=1) v += __shfl_xor(v, off);
    p[e]=v;
  }
  float m = -1e30f;
  #pragma unroll
  for(int e=0;e<NE;e++){ p[e] += bg[e]; m = fmaxf(m, p[e]); }
  float s = 0.f;
  #pragma unroll
  for(int e=0;e<NE;e++){ p[e] = __expf(p[e]-m); s += p[e]; }
  float inv = 1.f/s;
  float gsel = p[0];
  #pragma unroll
  for (int e=1;e<NE;e++) gsel = (lane==e) ? p[e] : gsel;
  gsel *= inv;
  if (lane < NE) gates[(size_t)n*NE + lane] = gsel;
  u16* xrow = xb + (size_t)n*XBW;
  union { u16 u[8]; short8 v; } lo, hi;
  #pragma unroll
  for(int j=0;j<4;j++){
    lo.u[j]   = f2bf((&xl0.x)[j]);  lo.u[j+4] = f2bf((&xl1.x)[j]);
    hi.u[j]   = f2bf((&xh0.x)[j]);  hi.u[j+4] = f2bf((&xh1.x)[j]);
  }
  *(short8*)(xrow + lane*8)       = lo.v;
  *(short8*)(xrow + 512 + lane*8) = hi.v;
  xrow[IN_DIM + lane] = (lane < NE) ? f2bf(gsel) : (u16)0;
}

// ---- We [8192k][1024o] fp32 -> WeT bf16 [1024o][8256k]; kb==127 blocks
//      also write the bias tail cols 8192..8255 (be or 0). ----
__global__ void k_wetT(const float* __restrict__ We, const float* __restrict__ be,
                       u16* __restrict__ WeT){
  __shared__ float tile[64][65];
  int kb = blockIdx.x & 127;
  int ob = blockIdx.x >> 7;
  int k0 = kb*64, o0 = ob*64;
  int tr = threadIdx.x >> 4;
  int tc = (threadIdx.x & 15) * 4;
  #pragma unroll
  for (int p=0;p<4;p++){
    int r = p*16 + tr;
    float4 v = *(const float4*)(We + (size_t)(k0+r)*OUT_DIM + o0 + tc);
    tile[r][tc+0]=v.x; tile[r][tc+1]=v.y; tile[r][tc+2]=v.z; tile[r][tc+3]=v.w;
  }
  __syncthreads();
  #pragma unroll
  for (int p=0;p<4;p++){
    int r = p*16 + tr;              // o_local
    ushort4 o;
    o.x = f2bf(tile[tc+0][r]);
    o.y = f2bf(tile[tc+1][r]);
    o.z = f2bf(tile[tc+2][r]);
    o.w = f2bf(tile[tc+3][r]);
    *(ushort4*)(WeT + (size_t)(o0+r)*KTOT + k0 + tc) = o;
  }
  if (kb == 127){
    int tr2 = threadIdx.x >> 2;          // 0..63
    int tc2 = (threadIdx.x & 3) * 16;    // 0,16,32,48
    int o = o0 + tr2;
    #pragma unroll
    for (int c2=0;c2<16;c2++){
      int c = tc2 + c2;
      WeT[(size_t)o*KTOT + KE + c] = (c < NE) ? f2bf(be[(size_t)c*OUT_DIM + o]) : (u16)0;
    }
  }
}

// ---- GEMM: out = sum_e g[n,e]*(xb @ We[e]) + g @ be  ----
// A = xb (unscaled bf16 x, L2/L3-resident); gate folded into acc via per-row
// Horner rescale at expert boundaries (t%16==0): acc *= s_{e-1}/s_e, final
// acc *= s_8 before the bias tile (t=128: xb pad-cols @ WeT bias-cols).
// Schedule identical to R4 (verified): BM=256,BN=128,BK=64, 512thr (8 waves,
// 4Mx2N 64x64), triple-buffer LDS, 2 phases/tile, counted vmcnt(6) (T3+T4),
// XOR-swizzle (T2), setprio (T5), XCD bm-chunk swizzle (T1).
__global__ __launch_bounds__(512,2) void k_gemm(const u16* __restrict__ xb,
      const u16* __restrict__ Wt, const float* __restrict__ gates,
      float* __restrict__ C){
  __shared__ u16 sA[3][BM*BK];   // 3 x 32KB
  __shared__ u16 sB[3][BN*BK];   // 3 x 16KB   total 144KB
  int tid = threadIdx.x;
  int wave = tid>>6, lane = tid&63;
  int g = (blockIdx.x & 7)*32 + (blockIdx.x >> 3);   // XCD chunk
  int bm = g >> 3;        // 0..31
  int bn = g & 7;         // 0..7
  int wr = wave>>1, wc = wave&1;     // 4M x 2N

  // staging: 512 thr x 16B; A tile 32KB = 4 shots, B 16KB = 2 shots
  int r8 = tid>>3, gl = tid&7;
  const u16* pAb[4]; const u16* pBb[2];
  int ldsA[4], ldsB[2];
  #pragma unroll
  for (int q=0;q<4;q++){
    int r = q*64 + r8;
    pAb[q] = xb + (size_t)(bm*BM + r)*XBW + ((gl ^ (r&7))<<3);
    ldsA[q] = r*BK + gl*8;
  }
  #pragma unroll
  for (int q=0;q<2;q++){
    int r = q*64 + r8;
    pBb[q] = Wt + (size_t)(bn*BN + r)*KTOT + ((gl ^ (r&7))<<3);
    ldsB[q] = r*BK + gl*8;
  }

  f32x4 acc[4][4];
  #pragma unroll
  for(int m=0;m<4;m++)
    #pragma unroll
    for(int n=0;n<4;n++)
      acc[m][n] = (f32x4){0.f,0.f,0.f,0.f};

  int rA0 = wr*64 + (lane&15);
  int rB0 = wc*64 + (lane&15);
  int krow = lane>>4;
  // per-lane accumulator rows: row0 + m*16 + j
  const float* gp2 = gates + (size_t)(bm*BM + wr*64 + (lane>>4)*4)*NE;

  // A k-offset for tile ts: expert tiles wrap mod 1024; bias tile = pad cols
  #define AKO(ts) ((ts) < 128 ? (((ts)&15)<<6) : IN_DIM)

  // prologue: stage tiles 0 and 1
  #pragma unroll
  for (int q=0;q<4;q++) gload16(pAb[q] + AKO(0), &sA[0][ldsA[q]]);
  #pragma unroll
  for (int q=0;q<2;q++) gload16(pBb[q],          &sB[0][ldsB[q]]);
  #pragma unroll
  for (int q=0;q<4;q++) gload16(pAb[q] + AKO(1), &sA[1][ldsA[q]]);
  #pragma unroll
  for (int q=0;q<2;q++) gload16(pBb[q] + 64,     &sB[1][ldsB[q]]);

  float gc[16];
  #pragma unroll
  for (int i=0;i<16;i++) gc[i] = gp2[(size_t)((i>>2)*16 + (i&3))*NE];  // expert 0

  asm volatile("s_waitcnt vmcnt(6)" ::: "memory");   // tile 0 landed
  __builtin_amdgcn_s_barrier();

  int cur = 0;
  for (int t=0; t<NKT; ++t){
    int nb = (cur==2) ? 0 : cur+1;
    int stage = (cur==0) ? 2 : cur-1;   // (t+2)%3
    const u16* sa = sA[cur];
    const u16* sb = sB[cur];

    // ---- gate Horner rescale at expert boundaries ----
    if (t == 128){
      #pragma unroll
      for (int m=0;m<4;m++)
        #pragma unroll
        for (int n=0;n<4;n++)
          #pragma unroll
          for (int j=0;j<4;j++)
            acc[m][n][j] *= gc[m*4+j];
    } else if (t && !(t & 15)){
      int e = t >> 4;
      float rt[16];
      #pragma unroll
      for (int i=0;i<16;i++){
        float gn = gp2[(size_t)((i>>2)*16 + (i&3))*NE + e];
        rt[i] = gc[i] / gn;
        gc[i] = gn;
      }
      #pragma unroll
      for (int m=0;m<4;m++)
        #pragma unroll
        for (int n=0;n<4;n++)
          #pragma unroll
          for (int j=0;j<4;j++)
            acc[m][n][j] *= rt[m*4+j];
    }

    int ts = t + 2;
    #pragma unroll
    for (int ph=0; ph<2; ++ph){
      int kk = ph*32;
      short8 af[4], bfr[4];
      int g0 = (kk>>3) + krow;
      #pragma unroll
      for (int m=0;m<4;m++){
        int R = rA0 + m*16;
        af[m] = *(const short8*)(sa + R*BK + ((g0 ^ (R&7))<<3));
      }
      #pragma unroll
      for (int n=0;n<4;n++){
        int R = rB0 + n*16;
        bfr[n] = *(const short8*)(sb + R*BK + ((g0 ^ (R&7))<<3));
      }
      if (ts < NKT){
        if (ph==0){
          gload16(pAb[0] + AKO(ts), &sA[stage][ldsA[0]]);
          gload16(pAb[1] + AKO(ts), &sA[stage][ldsA[1]]);
          gload16(pBb[0] + ts*64,   &sB[stage][ldsB[0]]);
        } else {
          gload16(pAb[2] + AKO(ts), &sA[stage][ldsA[2]]);
          gload16(pAb[3] + AKO(ts), &sA[stage][ldsA[3]]);
          gload16(pBb[1] + ts*64,   &sB[stage][ldsB[1]]);
        }
      }
      __builtin_amdgcn_s_barrier();
      __builtin_amdgcn_s_setprio(1);
      #pragma unroll
      for (int m=0;m<4;m++)
        #pragma unroll
        for (int n=0;n<4;n++)
          acc[m][n] = __builtin_amdgcn_mfma_f32_16x16x32_bf16(af[m], bfr[n], acc[m][n], 0,0,0);
      __builtin_amdgcn_s_setprio(0);
      if (ph==0){
        __builtin_amdgcn_s_barrier();
      } else {
        // publish tile t+1's stage before anyone reads it
        if (t <= NKT-3) asm volatile("s_waitcnt vmcnt(6)" ::: "memory");
        else            asm volatile("s_waitcnt vmcnt(0)" ::: "memory");
        __builtin_amdgcn_s_barrier();
      }
    }
    cur = nb;
  }

  // epilogue: C/D layout col=lane&15, row=(lane>>4)*4+reg
  int row0 = bm*BM + wr*64 + (lane>>4)*4;
  int col0 = bn*BN + wc*64 + (lane&15);
  #pragma unroll
  for (int m=0;m<4;m++)
    #pragma unroll
    for (int n=0;n<4;n++)
      #pragma unroll
      for (int j=0;j<4;j++)
        C[(size_t)(row0 + m*16 + j)*OUT_DIM + col0 + n*16] = acc[m][n][j];
}

extern "C" void kernel_launch(void* const* d_in, const int* in_sizes, int n_in,
                              void* d_out, int out_size, void* d_ws, size_t ws_size,
                              hipStream_t stream){
  const float* x  = (const float*)d_in[0];
  const float* We = (const float*)d_in[1];
  const float* be = (const float*)d_in[2];
  const float* Wg = (const float*)d_in[3];
  const float* bg = (const float*)d_in[4];
  float* out = (float*)d_out;
  char* ws = (char*)d_ws;
  // ws: gates f32 [8192][8] 256KB | xb bf16 [8192][1088] 17.8MB
  //     | WeT bf16 [1024][8256] 16.9MB   (~35MB total)
  float* gates = (float*)ws;
  u16* xbuf = (u16*)(ws + (256<<10));
  u16* WeT  = (u16*)(ws + (256<<10) + (size_t)NT*XBW*2);

  k_gx  <<<NT/4, 256, 0, stream>>>(x, Wg, bg, gates, xbuf);
  k_wetT<<<(KE/64)*(OUT_DIM/64), 256, 0, stream>>>(We, be, WeT);
  k_gemm<<<(NT/BM)*(OUT_DIM/BN), 512, 0, stream>>>(xbuf, WeT, gates, out);
}

// Round 7
// 286.718 us; speedup vs baseline: 1.1614x; 1.1614x over previous
//
#include <hip/hip_runtime.h>
#include <hip/hip_bf16.h>

#define IN_DIM 1024
#define OUT_DIM 1024
#define NE 8
#define NT 8192
#define KE (NE*IN_DIM)      // 8192
#define KPAD 64
#define KTOT (KE+KPAD)      // 8256 (WeT width, incl bias cols)
#define XBW (IN_DIM+64)     // 1088 (xb width: 1024 x + 64 gate-pad)
#define BM 256
#define BN 128
#define BK 64
#define NKT 129             // 128 expert tiles + 1 bias tile

typedef unsigned short u16;
typedef __attribute__((ext_vector_type(4))) float f32x4;
typedef __attribute__((ext_vector_type(8))) short short8;

__device__ inline u16 f2bf(float f){
  unsigned u = __float_as_uint(f);
  return (u16)((u + 0x7fffu + ((u>>16)&1u)) >> 16);   // RNE
}

__device__ inline void gload16(const void* g, void* l){
  __builtin_amdgcn_global_load_lds(
    (const __attribute__((address_space(1))) void*)g,
    (__attribute__((address_space(3))) void*)l, 16, 0, 0);
}

// ---- fused: gates = softmax(x@Wg+bg) (f32); xb[n][k]=bf16(x[n,k]);
//      xb[n][1024+c] = bf16(gate_c) (c<8) else 0.  One wave per token. ----
__global__ void k_gx(const float* __restrict__ x, const float* __restrict__ Wg,
                     const float* __restrict__ bg, float* __restrict__ gates,
                     u16* __restrict__ xb){
  int lane = threadIdx.x & 63;
  int n = blockIdx.x*4 + (threadIdx.x>>6);
  const float* xr = x + (size_t)n*IN_DIM;
  float4 xl0 = *(const float4*)(xr + lane*8);
  float4 xl1 = *(const float4*)(xr + lane*8 + 4);
  float4 xh0 = *(const float4*)(xr + 512 + lane*8);
  float4 xh1 = *(const float4*)(xr + 512 + lane*8 + 4);
  float p[NE];
  #pragma unroll
  for(int e=0;e<NE;e++) p[e]=0.f;
  const float* wl = Wg + (size_t)(lane*8)*NE;
  const float* wh = Wg + (size_t)(512 + lane*8)*NE;
  #pragma unroll
  for(int j=0;j<4;j++){
    #pragma unroll
    for(int e=0;e<NE;e++){
      p[e] = fmaf((&xl0.x)[j], wl[(size_t)j*NE+e], p[e]);
      p[e] = fmaf((&xh0.x)[j], wh[(size_t)j*NE+e], p[e]);
      p[e] = fmaf((&xl1.x)[j], wl[(size_t)(j+4)*NE+e], p[e]);
      p[e] = fmaf((&xh1.x)[j], wh[(size_t)(j+4)*NE+e], p[e]);
    }
  }
  #pragma unroll
  for(int e=0;e<NE;e++){
    float v = p[e];
    #pragma unroll
    for(int off=32;off;off>>=1) v += __shfl_xor(v, off);
    p[e]=v;
  }
  float m = -1e30f;
  #pragma unroll
  for(int e=0;e<NE;e++){ p[e] += bg[e]; m = fmaxf(m, p[e]); }
  float s = 0.f;
  #pragma unroll
  for(int e=0;e<NE;e++){ p[e] = __expf(p[e]-m); s += p[e]; }
  float inv = 1.f/s;
  float gsel = p[0];
  #pragma unroll
  for (int e=1;e<NE;e++) gsel = (lane==e) ? p[e] : gsel;
  gsel *= inv;
  if (lane < NE) gates[(size_t)n*NE + lane] = gsel;
  u16* xrow = xb + (size_t)n*XBW;
  union { u16 u[8]; short8 v; } lo, hi;
  #pragma unroll
  for(int j=0;j<4;j++){
    lo.u[j]   = f2bf((&xl0.x)[j]);  lo.u[j+4] = f2bf((&xl1.x)[j]);
    hi.u[j]   = f2bf((&xh0.x)[j]);  hi.u[j+4] = f2bf((&xh1.x)[j]);
  }
  *(short8*)(xrow + lane*8)       = lo.v;
  *(short8*)(xrow + 512 + lane*8) = hi.v;
  xrow[IN_DIM + lane] = (lane < NE) ? f2bf(gsel) : (u16)0;
}

// ---- We [8192k][1024o] fp32 -> WeT bf16 [1024o][8256k]; kb==127 blocks
//      also write the bias tail cols 8192..8255 (be or 0). ----
__global__ void k_wetT(const float* __restrict__ We, const float* __restrict__ be,
                       u16* __restrict__ WeT){
  __shared__ float tile[64][65];
  int kb = blockIdx.x & 127;
  int ob = blockIdx.x >> 7;
  int k0 = kb*64, o0 = ob*64;
  int tr = threadIdx.x >> 4;
  int tc = (threadIdx.x & 15) * 4;
  #pragma unroll
  for (int p=0;p<4;p++){
    int r = p*16 + tr;
    float4 v = *(const float4*)(We + (size_t)(k0+r)*OUT_DIM + o0 + tc);
    tile[r][tc+0]=v.x; tile[r][tc+1]=v.y; tile[r][tc+2]=v.z; tile[r][tc+3]=v.w;
  }
  __syncthreads();
  #pragma unroll
  for (int p=0;p<4;p++){
    int r = p*16 + tr;              // o_local
    ushort4 o;
    o.x = f2bf(tile[tc+0][r]);
    o.y = f2bf(tile[tc+1][r]);
    o.z = f2bf(tile[tc+2][r]);
    o.w = f2bf(tile[tc+3][r]);
    *(ushort4*)(WeT + (size_t)(o0+r)*KTOT + k0 + tc) = o;
  }
  if (kb == 127){
    int tr2 = threadIdx.x >> 2;          // 0..63
    int tc2 = (threadIdx.x & 3) * 16;    // 0,16,32,48
    int o = o0 + tr2;
    #pragma unroll
    for (int c2=0;c2<16;c2++){
      int c = tc2 + c2;
      WeT[(size_t)o*KTOT + KE + c] = (c < NE) ? f2bf(be[(size_t)c*OUT_DIM + o]) : (u16)0;
    }
  }
}

// ---- GEMM: out = sum_e g[n,e]*(xb @ We[e]) + g @ be ----
// A = xb (unscaled bf16 x); gate folded via Horner rescale placed at
// COMPILE-TIME loop boundaries (e-loop x 16-tile inner loop; R5 lesson:
// an in-loop branch gets if-converted into ~450 predicated VALU/tile).
// Staging uses pure pointer bumps (uniform scalar +BK or +BK-IN_DIM wrap).
// Inner body = R4's verified schedule: BM=256,BN=128,BK=64, 512thr (8 waves
// 4Mx2N 64x64), triple-buffer LDS, 2 phases/tile, counted vmcnt(6) (T3+T4),
// XOR-swizzle (T2), setprio (T5), XCD bm-chunk swizzle (T1).
__global__ __launch_bounds__(512,2) void k_gemm(const u16* __restrict__ xb,
      const u16* __restrict__ Wt, const float* __restrict__ gates,
      float* __restrict__ C){
  __shared__ u16 sA[3][BM*BK];   // 3 x 32KB
  __shared__ u16 sB[3][BN*BK];   // 3 x 16KB   total 144KB
  int tid = threadIdx.x;
  int wave = tid>>6, lane = tid&63;
  int g = (blockIdx.x & 7)*32 + (blockIdx.x >> 3);   // XCD chunk
  int bm = g >> 3;        // 0..31
  int bn = g & 7;         // 0..7
  int wr = wave>>1, wc = wave&1;     // 4M x 2N

  // staging: 512 thr x 16B; A tile 32KB = 4 shots, B 16KB = 2 shots
  int r8 = tid>>3, gl = tid&7;
  const u16* pAs[4]; const u16* pBs[2];
  int ldsA[4], ldsB[2];
  #pragma unroll
  for (int q=0;q<4;q++){
    int r = q*64 + r8;
    pAs[q] = xb + (size_t)(bm*BM + r)*XBW + ((gl ^ (r&7))<<3);
    ldsA[q] = r*BK + gl*8;
  }
  #pragma unroll
  for (int q=0;q<2;q++){
    int r = q*64 + r8;
    pBs[q] = Wt + (size_t)(bn*BN + r)*KTOT + ((gl ^ (r&7))<<3);
    ldsB[q] = r*BK + gl*8;
  }

  f32x4 acc[4][4];
  #pragma unroll
  for(int m=0;m<4;m++)
    #pragma unroll
    for(int n=0;n<4;n++)
      acc[m][n] = (f32x4){0.f,0.f,0.f,0.f};

  int rA0 = wr*64 + (lane&15);
  int rB0 = wc*64 + (lane&15);
  int krow = lane>>4;
  const float* gp2 = gates + (size_t)(bm*BM + wr*64 + (lane>>4)*4)*NE;

  // prologue: stage tiles 0,1; pointer-bump after each (ts0->1->2: +BK)
  #pragma unroll
  for (int q=0;q<4;q++){ gload16(pAs[q], &sA[0][ldsA[q]]); pAs[q] += BK; }
  #pragma unroll
  for (int q=0;q<2;q++){ gload16(pBs[q], &sB[0][ldsB[q]]); pBs[q] += BK; }
  #pragma unroll
  for (int q=0;q<4;q++){ gload16(pAs[q], &sA[1][ldsA[q]]); pAs[q] += BK; }
  #pragma unroll
  for (int q=0;q<2;q++){ gload16(pBs[q], &sB[1][ldsB[q]]); pBs[q] += BK; }

  float gc[16];
  #pragma unroll
  for (int i=0;i<16;i++) gc[i] = gp2[(size_t)((i>>2)*16 + (i&3))*NE];  // expert 0

  asm volatile("s_waitcnt vmcnt(6)" ::: "memory");   // tile 0 landed
  __builtin_amdgcn_s_barrier();

  int cur = 0;
  int t = 0;
  for (int e=0; e<NE; ++e){
    if (e){
      // Horner rescale: acc *= g_{e-1}/g_e  (runs 7x, OUTSIDE the hot loop)
      float rt[16];
      #pragma unroll
      for (int i=0;i<16;i++){
        float gn = gp2[(size_t)((i>>2)*16 + (i&3))*NE + e];
        rt[i] = gc[i] / gn;
        gc[i] = gn;
      }
      #pragma unroll
      for (int m=0;m<4;m++)
        #pragma unroll
        for (int n=0;n<4;n++)
          #pragma unroll
          for (int j=0;j<4;j++)
            acc[m][n][j] *= rt[m*4+j];
    }
    for (int tt=0; tt<16; ++tt, ++t){
      int nb = (cur==2) ? 0 : cur+1;
      int stage = (cur==0) ? 2 : cur-1;   // (t+2)%3
      const u16* sa = sA[cur];
      const u16* sb = sB[cur];
      int ts = t + 2;
      // A staging bump for NEXT stage (ts->ts+1): wrap at expert k-boundary
      int bumpA = ((((ts+1)&15)==0) && (ts+1)!=128) ? (BK-IN_DIM) : BK;
      #pragma unroll
      for (int ph=0; ph<2; ++ph){
        int kk = ph*32;
        short8 af[4], bfr[4];
        int g0 = (kk>>3) + krow;
        #pragma unroll
        for (int m=0;m<4;m++){
          int R = rA0 + m*16;
          af[m] = *(const short8*)(sa + R*BK + ((g0 ^ (R&7))<<3));
        }
        #pragma unroll
        for (int n=0;n<4;n++){
          int R = rB0 + n*16;
          bfr[n] = *(const short8*)(sb + R*BK + ((g0 ^ (R&7))<<3));
        }
        if (ts < NKT){
          if (ph==0){
            gload16(pAs[0], &sA[stage][ldsA[0]]); pAs[0] += bumpA;
            gload16(pAs[1], &sA[stage][ldsA[1]]); pAs[1] += bumpA;
            gload16(pBs[0], &sB[stage][ldsB[0]]); pBs[0] += BK;
          } else {
            gload16(pAs[2], &sA[stage][ldsA[2]]); pAs[2] += bumpA;
            gload16(pAs[3], &sA[stage][ldsA[3]]); pAs[3] += bumpA;
            gload16(pBs[1], &sB[stage][ldsB[1]]); pBs[1] += BK;
          }
        }
        __builtin_amdgcn_s_barrier();
        __builtin_amdgcn_s_setprio(1);
        #pragma unroll
        for (int m=0;m<4;m++)
          #pragma unroll
          for (int n=0;n<4;n++)
            acc[m][n] = __builtin_amdgcn_mfma_f32_16x16x32_bf16(af[m], bfr[n], acc[m][n], 0,0,0);
        __builtin_amdgcn_s_setprio(0);
        if (ph==0){
          __builtin_amdgcn_s_barrier();
        } else {
          if (t <= NKT-3) asm volatile("s_waitcnt vmcnt(6)" ::: "memory");
          else            asm volatile("s_waitcnt vmcnt(0)" ::: "memory");
          __builtin_amdgcn_s_barrier();
        }
      }
      cur = nb;
    }
  }

  // final scale by g_7, then peeled bias tile (t=128; staged & published
  // during t=126/127; no staging or barriers needed here)
  #pragma unroll
  for (int m=0;m<4;m++)
    #pragma unroll
    for (int n=0;n<4;n++)
      #pragma unroll
      for (int j=0;j<4;j++)
        acc[m][n][j] *= gc[m*4+j];
  {
    const u16* sa = sA[cur];
    const u16* sb = sB[cur];
    #pragma unroll
    for (int ph=0; ph<2; ++ph){
      int kk = ph*32;
      short8 af[4], bfr[4];
      int g0 = (kk>>3) + krow;
      #pragma unroll
      for (int m=0;m<4;m++){
        int R = rA0 + m*16;
        af[m] = *(const short8*)(sa + R*BK + ((g0 ^ (R&7))<<3));
      }
      #pragma unroll
      for (int n=0;n<4;n++){
        int R = rB0 + n*16;
        bfr[n] = *(const short8*)(sb + R*BK + ((g0 ^ (R&7))<<3));
      }
      #pragma unroll
      for (int m=0;m<4;m++)
        #pragma unroll
        for (int n=0;n<4;n++)
          acc[m][n] = __builtin_amdgcn_mfma_f32_16x16x32_bf16(af[m], bfr[n], acc[m][n], 0,0,0);
    }
  }

  // epilogue: C/D layout col=lane&15, row=(lane>>4)*4+reg
  int row0 = bm*BM + wr*64 + (lane>>4)*4;
  int col0 = bn*BN + wc*64 + (lane&15);
  #pragma unroll
  for (int m=0;m<4;m++)
    #pragma unroll
    for (int n=0;n<4;n++)
      #pragma unroll
      for (int j=0;j<4;j++)
        C[(size_t)(row0 + m*16 + j)*OUT_DIM + col0 + n*16] = acc[m][n][j];
}

extern "C" void kernel_launch(void* const* d_in, const int* in_sizes, int n_in,
                              void* d_out, int out_size, void* d_ws, size_t ws_size,
                              hipStream_t stream){
  const float* x  = (const float*)d_in[0];
  const float* We = (const float*)d_in[1];
  const float* be = (const float*)d_in[2];
  const float* Wg = (const float*)d_in[3];
  const float* bg = (const float*)d_in[4];
  float* out = (float*)d_out;
  char* ws = (char*)d_ws;
  // ws: gates f32 [8192][8] 256KB | xb bf16 [8192][1088] 17.8MB
  //     | WeT bf16 [1024][8256] 16.9MB   (~35MB total)
  float* gates = (float*)ws;
  u16* xbuf = (u16*)(ws + (256<<10));
  u16* WeT  = (u16*)(ws + (256<<10) + (size_t)NT*XBW*2);

  k_gx  <<<NT/4, 256, 0, stream>>>(x, Wg, bg, gates, xbuf);
  k_wetT<<<(KE/64)*(OUT_DIM/64), 256, 0, stream>>>(We, be, WeT);
  k_gemm<<<(NT/BM)*(OUT_DIM/BN), 512, 0, stream>>>(xbuf, WeT, gates, out);
}

// Round 11
// 251.263 us; speedup vs baseline: 1.3253x; 1.1411x over previous
//
#include <hip/hip_runtime.h>
#include <hip/hip_bf16.h>

#define IN_DIM 1024
#define OUT_DIM 1024
#define NE 8
#define NT 8192
#define KE (NE*IN_DIM)      // 8192
#define KPAD 64
#define KTOT (KE+KPAD)      // 8256 (WeT width, incl bias cols)
#define XBW (IN_DIM+64)     // 1088 (xb width: 1024 x + 64 gate-pad)
#define BM 256
#define BN 128
#define BK 64
#define NKT 129             // 128 expert tiles + 1 bias tile
#define GXBLK (NT/4)        // 2048 gate/cast blocks

typedef unsigned short u16;
typedef __attribute__((ext_vector_type(4))) float f32x4;
typedef __attribute__((ext_vector_type(8))) short short8;

__device__ inline u16 f2bf(float f){
  unsigned u = __float_as_uint(f);
  return (u16)((u + 0x7fffu + ((u>>16)&1u)) >> 16);   // RNE
}

__device__ inline void gload16(const void* g, void* l){
  __builtin_amdgcn_global_load_lds(
    (const __attribute__((address_space(1))) void*)g,
    (__attribute__((address_space(3))) void*)l, 16, 0, 0);
}

// ---- merged prep: blocks [0,2048): gates+xb cast; [2048,4096): We transpose.
// gx half (R7 lesson): stride-64 k-ownership makes ALL accesses coalesced —
// x scalar 4B (256B/wave), Wg two float4 at 32B lane-stride, xb 2B store.
__global__ void k_prep(const float* __restrict__ x, const float* __restrict__ Wg,
                       const float* __restrict__ bg, const float* __restrict__ We,
                       const float* __restrict__ be, float* __restrict__ gates,
                       u16* __restrict__ xb, u16* __restrict__ WeT){
  __shared__ float tile[64][65];     // used by transpose half only
  if (blockIdx.x < GXBLK){
    int lane = threadIdx.x & 63;
    int n = blockIdx.x*4 + (threadIdx.x>>6);
    const float* xr = x + (size_t)n*IN_DIM;
    u16* xrow = xb + (size_t)n*XBW;
    float p[NE];
    #pragma unroll
    for(int e=0;e<NE;e++) p[e]=0.f;
    #pragma unroll
    for (int u=0; u<16; ++u){
      int k = u*64 + lane;
      float xv = xr[k];
      float4 w0 = *(const float4*)(Wg + (size_t)k*NE);
      float4 w1 = *(const float4*)(Wg + (size_t)k*NE + 4);
      p[0] = fmaf(xv, w0.x, p[0]);  p[1] = fmaf(xv, w0.y, p[1]);
      p[2] = fmaf(xv, w0.z, p[2]);  p[3] = fmaf(xv, w0.w, p[3]);
      p[4] = fmaf(xv, w1.x, p[4]);  p[5] = fmaf(xv, w1.y, p[5]);
      p[6] = fmaf(xv, w1.z, p[6]);  p[7] = fmaf(xv, w1.w, p[7]);
      xrow[k] = f2bf(xv);
    }
    #pragma unroll
    for(int e=0;e<NE;e++){
      float v = p[e];
      #pragma unroll
      for(int off=32;off;off>>=1) v += __shfl_xor(v, off);
      p[e]=v;
    }
    float m = -1e30f;
    #pragma unroll
    for(int e=0;e<NE;e++){ p[e] += bg[e]; m = fmaxf(m, p[e]); }
    float s = 0.f;
    #pragma unroll
    for(int e=0;e<NE;e++){ p[e] = __expf(p[e]-m); s += p[e]; }
    float inv = 1.f/s;
    float gsel = p[0];
    #pragma unroll
    for (int e=1;e<NE;e++) gsel = (lane==e) ? p[e] : gsel;
    gsel *= inv;
    if (lane < NE) gates[(size_t)n*NE + lane] = gsel;
    xrow[IN_DIM + lane] = (lane < NE) ? f2bf(gsel) : (u16)0;
  } else {
    int bid = blockIdx.x - GXBLK;
    int kb = bid & 127;
    int ob = bid >> 7;
    int k0 = kb*64, o0 = ob*64;
    int tr = threadIdx.x >> 4;
    int tc = (threadIdx.x & 15) * 4;
    #pragma unroll
    for (int p=0;p<4;p++){
      int r = p*16 + tr;
      float4 v = *(const float4*)(We + (size_t)(k0+r)*OUT_DIM + o0 + tc);
      tile[r][tc+0]=v.x; tile[r][tc+1]=v.y; tile[r][tc+2]=v.z; tile[r][tc+3]=v.w;
    }
    __syncthreads();
    #pragma unroll
    for (int p=0;p<4;p++){
      int r = p*16 + tr;              // o_local
      ushort4 o;
      o.x = f2bf(tile[tc+0][r]);
      o.y = f2bf(tile[tc+1][r]);
      o.z = f2bf(tile[tc+2][r]);
      o.w = f2bf(tile[tc+3][r]);
      *(ushort4*)(WeT + (size_t)(o0+r)*KTOT + k0 + tc) = o;
    }
    if (kb == 127){
      int tr2 = threadIdx.x >> 2;          // 0..63
      int tc2 = (threadIdx.x & 3) * 16;    // 0,16,32,48
      int o = o0 + tr2;
      #pragma unroll
      for (int c2=0;c2<16;c2++){
        int c = tc2 + c2;
        WeT[(size_t)o*KTOT + KE + c] = (c < NE) ? f2bf(be[(size_t)c*OUT_DIM + o]) : (u16)0;
      }
    }
  }
}

// ---- GEMM: out = sum_e g[n,e]*(xb @ We[e]) + g @ be ----
// BYTE-IDENTICAL to R7's verified kernel (153.7us, MfmaUtil 40.3%).
// A = xb (unscaled bf16 x); gate folded via Horner rescale at compile-time
// loop boundaries. BM=256,BN=128,BK=64, 512thr (8 waves 4Mx2N 64x64),
// triple-buffer LDS, 2 phases/tile, counted vmcnt(6) (T3+T4), XOR-swizzle
// (T2), setprio (T5), XCD bm-chunk swizzle (T1).
__global__ __launch_bounds__(512,2) void k_gemm(const u16* __restrict__ xb,
      const u16* __restrict__ Wt, const float* __restrict__ gates,
      float* __restrict__ C){
  __shared__ u16 sA[3][BM*BK];   // 3 x 32KB
  __shared__ u16 sB[3][BN*BK];   // 3 x 16KB   total 144KB
  int tid = threadIdx.x;
  int wave = tid>>6, lane = tid&63;
  int g = (blockIdx.x & 7)*32 + (blockIdx.x >> 3);   // XCD chunk
  int bm = g >> 3;        // 0..31
  int bn = g & 7;         // 0..7
  int wr = wave>>1, wc = wave&1;     // 4M x 2N

  // staging: 512 thr x 16B; A tile 32KB = 4 shots, B 16KB = 2 shots
  int r8 = tid>>3, gl = tid&7;
  const u16* pAs[4]; const u16* pBs[2];
  int ldsA[4], ldsB[2];
  #pragma unroll
  for (int q=0;q<4;q++){
    int r = q*64 + r8;
    pAs[q] = xb + (size_t)(bm*BM + r)*XBW + ((gl ^ (r&7))<<3);
    ldsA[q] = r*BK + gl*8;
  }
  #pragma unroll
  for (int q=0;q<2;q++){
    int r = q*64 + r8;
    pBs[q] = Wt + (size_t)(bn*BN + r)*KTOT + ((gl ^ (r&7))<<3);
    ldsB[q] = r*BK + gl*8;
  }

  f32x4 acc[4][4];
  #pragma unroll
  for(int m=0;m<4;m++)
    #pragma unroll
    for(int n=0;n<4;n++)
      acc[m][n] = (f32x4){0.f,0.f,0.f,0.f};

  int rA0 = wr*64 + (lane&15);
  int rB0 = wc*64 + (lane&15);
  int krow = lane>>4;
  const float* gp2 = gates + (size_t)(bm*BM + wr*64 + (lane>>4)*4)*NE;

  // prologue: stage tiles 0,1; pointer-bump after each (ts0->1->2: +BK)
  #pragma unroll
  for (int q=0;q<4;q++){ gload16(pAs[q], &sA[0][ldsA[q]]); pAs[q] += BK; }
  #pragma unroll
  for (int q=0;q<2;q++){ gload16(pBs[q], &sB[0][ldsB[q]]); pBs[q] += BK; }
  #pragma unroll
  for (int q=0;q<4;q++){ gload16(pAs[q], &sA[1][ldsA[q]]); pAs[q] += BK; }
  #pragma unroll
  for (int q=0;q<2;q++){ gload16(pBs[q], &sB[1][ldsB[q]]); pBs[q] += BK; }

  float gc[16];
  #pragma unroll
  for (int i=0;i<16;i++) gc[i] = gp2[(size_t)((i>>2)*16 + (i&3))*NE];  // expert 0

  asm volatile("s_waitcnt vmcnt(6)" ::: "memory");   // tile 0 landed
  __builtin_amdgcn_s_barrier();

  int cur = 0;
  int t = 0;
  for (int e=0; e<NE; ++e){
    if (e){
      // Horner rescale: acc *= g_{e-1}/g_e  (runs 7x, OUTSIDE the hot loop)
      float rt[16];
      #pragma unroll
      for (int i=0;i<16;i++){
        float gn = gp2[(size_t)((i>>2)*16 + (i&3))*NE + e];
        rt[i] = gc[i] / gn;
        gc[i] = gn;
      }
      #pragma unroll
      for (int m=0;m<4;m++)
        #pragma unroll
        for (int n=0;n<4;n++)
          #pragma unroll
          for (int j=0;j<4;j++)
            acc[m][n][j] *= rt[m*4+j];
    }
    for (int tt=0; tt<16; ++tt, ++t){
      int nb = (cur==2) ? 0 : cur+1;
      int stage = (cur==0) ? 2 : cur-1;   // (t+2)%3
      const u16* sa = sA[cur];
      const u16* sb = sB[cur];
      int ts = t + 2;
      // A staging bump for NEXT stage (ts->ts+1): wrap at expert k-boundary
      int bumpA = ((((ts+1)&15)==0) && (ts+1)!=128) ? (BK-IN_DIM) : BK;
      #pragma unroll
      for (int ph=0; ph<2; ++ph){
        int kk = ph*32;
        short8 af[4], bfr[4];
        int g0 = (kk>>3) + krow;
        #pragma unroll
        for (int m=0;m<4;m++){
          int R = rA0 + m*16;
          af[m] = *(const short8*)(sa + R*BK + ((g0 ^ (R&7))<<3));
        }
        #pragma unroll
        for (int n=0;n<4;n++){
          int R = rB0 + n*16;
          bfr[n] = *(const short8*)(sb + R*BK + ((g0 ^ (R&7))<<3));
        }
        if (ts < NKT){
          if (ph==0){
            gload16(pAs[0], &sA[stage][ldsA[0]]); pAs[0] += bumpA;
            gload16(pAs[1], &sA[stage][ldsA[1]]); pAs[1] += bumpA;
            gload16(pBs[0], &sB[stage][ldsB[0]]); pBs[0] += BK;
          } else {
            gload16(pAs[2], &sA[stage][ldsA[2]]); pAs[2] += bumpA;
            gload16(pAs[3], &sA[stage][ldsA[3]]); pAs[3] += bumpA;
            gload16(pBs[1], &sB[stage][ldsB[1]]); pBs[1] += BK;
          }
        }
        __builtin_amdgcn_s_barrier();
        __builtin_amdgcn_s_setprio(1);
        #pragma unroll
        for (int m=0;m<4;m++)
          #pragma unroll
          for (int n=0;n<4;n++)
            acc[m][n] = __builtin_amdgcn_mfma_f32_16x16x32_bf16(af[m], bfr[n], acc[m][n], 0,0,0);
        __builtin_amdgcn_s_setprio(0);
        if (ph==0){
          __builtin_amdgcn_s_barrier();
        } else {
          if (t <= NKT-3) asm volatile("s_waitcnt vmcnt(6)" ::: "memory");
          else            asm volatile("s_waitcnt vmcnt(0)" ::: "memory");
          __builtin_amdgcn_s_barrier();
        }
      }
      cur = nb;
    }
  }

  // final scale by g_7, then peeled bias tile (t=128; staged & published
  // during t=126/127; no staging or barriers needed here)
  #pragma unroll
  for (int m=0;m<4;m++)
    #pragma unroll
    for (int n=0;n<4;n++)
      #pragma unroll
      for (int j=0;j<4;j++)
        acc[m][n][j] *= gc[m*4+j];
  {
    const u16* sa = sA[cur];
    const u16* sb = sB[cur];
    #pragma unroll
    for (int ph=0; ph<2; ++ph){
      int kk = ph*32;
      short8 af[4], bfr[4];
      int g0 = (kk>>3) + krow;
      #pragma unroll
      for (int m=0;m<4;m++){
        int R = rA0 + m*16;
        af[m] = *(const short8*)(sa + R*BK + ((g0 ^ (R&7))<<3));
      }
      #pragma unroll
      for (int n=0;n<4;n++){
        int R = rB0 + n*16;
        bfr[n] = *(const short8*)(sb + R*BK + ((g0 ^ (R&7))<<3));
      }
      #pragma unroll
      for (int m=0;m<4;m++)
        #pragma unroll
        for (int n=0;n<4;n++)
          acc[m][n] = __builtin_amdgcn_mfma_f32_16x16x32_bf16(af[m], bfr[n], acc[m][n], 0,0,0);
    }
  }

  // epilogue: C/D layout col=lane&15, row=(lane>>4)*4+reg
  int row0 = bm*BM + wr*64 + (lane>>4)*4;
  int col0 = bn*BN + wc*64 + (lane&15);
  #pragma unroll
  for (int m=0;m<4;m++)
    #pragma unroll
    for (int n=0;n<4;n++)
      #pragma unroll
      for (int j=0;j<4;j++)
        C[(size_t)(row0 + m*16 + j)*OUT_DIM + col0 + n*16] = acc[m][n][j];
}

extern "C" void kernel_launch(void* const* d_in, const int* in_sizes, int n_in,
                              void* d_out, int out_size, void* d_ws, size_t ws_size,
                              hipStream_t stream){
  const float* x  = (const float*)d_in[0];
  const float* We = (const float*)d_in[1];
  const float* be = (const float*)d_in[2];
  const float* Wg = (const float*)d_in[3];
  const float* bg = (const float*)d_in[4];
  float* out = (float*)d_out;
  char* ws = (char*)d_ws;
  // ws: gates f32 [8192][8] 256KB | xb bf16 [8192][1088] 17.8MB
  //     | WeT bf16 [1024][8256] 16.9MB   (~35MB total)
  float* gates = (float*)ws;
  u16* xbuf = (u16*)(ws + (256<<10));
  u16* WeT  = (u16*)(ws + (256<<10) + (size_t)NT*XBW*2);

  k_prep<<<GXBLK + (KE/64)*(OUT_DIM/64), 256, 0, stream>>>(x, Wg, bg, We, be, gates, xbuf, WeT);
  k_gemm<<<(NT/BM)*(OUT_DIM/BN), 512, 0, stream>>>(xbuf, WeT, gates, out);
}